// Round 3
// baseline (43.310 us; speedup 1.0000x reference)
//
#include <hip/hip_runtime.h>

// QueryAndGroup: ball_query(r=0.2, nsample=32) + group xyz (centered) + group features.
// B=4, N=16384, M=2048, C=64. Output (B, 67, M, 32) f32.
//
// Kernel 1 (prep): block-role split, two independent jobs run CONCURRENTLY:
//   - blocks [0, 1024):  transpose feat (B,C,N) -> featT (B,N,C) in d_ws
//   - blocks [1024, 3072): ball-query scan, one wave per query, writes the
//     32 selected indices to idx_ws (ballot/prefix-popcount, early exit)
//   This overlaps the memory-streaming transpose with the latency-bound scan.
// Kernel 2 (gather): one wave per query; coalesced idx read, 8 independent
//   float4 loads from featT's contiguous 256B rows, s-coalesced stores.

#define WPB 4
constexpr int Bc = 4, Nc = 16384, Mc = 2048, Cc = 64, Sc = 32;
constexpr int TBLOCKS = (Nc / 64) * Bc;   // 1024 transpose blocks
constexpr int SBLOCKS = (Bc * Mc) / WPB;  // 2048 scan blocks

__global__ __launch_bounds__(256) void prep_kernel(
    const float* __restrict__ xyz,      // (B, N, 3)
    const float* __restrict__ new_xyz,  // (B, M, 3)
    const float* __restrict__ feat,     // (B, C, N)
    float* __restrict__ featT,          // (B, N, C)
    int* __restrict__ idxws)            // (B*M, 32)
{
#pragma clang fp contract(off)
    __shared__ float tile[64][65];

    if (blockIdx.x < TBLOCKS) {
        // ---- transpose role ----
        const int b = blockIdx.x >> 8;               // / (Nc/64)
        const int nbase = (blockIdx.x & 255) * 64;
        const int tn = threadIdx.x & 63;
        const int tq = threadIdx.x >> 6;             // 0..3
        const float* fb = feat + (size_t)b * Cc * Nc;
        float* ob = featT + (size_t)b * Nc * Cc;
        #pragma unroll
        for (int k = 0; k < 16; ++k) {
            const int c = k * 4 + tq;
            tile[tn][c] = fb[(size_t)c * Nc + nbase + tn];      // coalesced reads
        }
        __syncthreads();
        #pragma unroll
        for (int k = 0; k < 16; ++k) {
            const int nl = k * 4 + tq;
            ob[(size_t)(nbase + nl) * Cc + tn] = tile[nl][tn];  // coalesced writes
        }
        return;
    }

    // ---- ball-query scan role ----
    const int sb   = blockIdx.x - TBLOCKS;
    const int lane = threadIdx.x & 63;
    const int wv   = threadIdx.x >> 6;
    const int q    = sb * WPB + wv;
    const int b    = q >> 11;            // / Mc
    const int m    = q & (Mc - 1);

    const float r2 = 0.2f * 0.2f;
    const float* nz = new_xyz + (size_t)(b * Mc + m) * 3;
    const float qx = nz[0], qy = nz[1], qz = nz[2];
    const float* xb = xyz + (size_t)b * Nc * 3;
    int* myidx = idxws + (size_t)q * Sc;

    int count = 0, firstIdx = 0;
    const unsigned long long lt = (1ull << lane) - 1ull;
    for (int base = 0; base < Nc; base += 256) {
        float px[4], py[4], pz[4];
        #pragma unroll
        for (int u = 0; u < 4; ++u) {      // batch 12 loads: 1 latency per 256 pts
            const float* pp = xb + (size_t)(base + u * 64 + lane) * 3;
            px[u] = pp[0]; py[u] = pp[1]; pz[u] = pp[2];
        }
        #pragma unroll
        for (int u = 0; u < 4; ++u) {
            const float dx = qx - px[u], dy = qy - py[u], dz = qz - pz[u];
            float d2 = dx * dx + dy * dy;  // no fma: match np/jax f32 rounding
            d2 = d2 + dz * dz;
            const bool in = d2 < r2;
            const unsigned long long mask = __ballot(in);
            if (in) {
                const int slot = count + __popcll(mask & lt);
                if (slot < Sc) myidx[slot] = base + u * 64 + lane;
            }
            if (count == 0 && mask != 0ull)
                firstIdx = base + u * 64 + __builtin_ctzll(mask);
            count += __popcll(mask);
        }
        if (count >= Sc) break;            // wave-uniform
    }
    const int start = count < Sc ? count : Sc;
    if (start + lane < Sc) myidx[start + lane] = firstIdx;
}

__global__ __launch_bounds__(256) void gather_kernel(
    const float* __restrict__ xyz,      // (B, N, 3)
    const float* __restrict__ new_xyz,  // (B, M, 3)
    const float* __restrict__ featT,    // (B, N, C)
    const int* __restrict__ idxws,      // (B*M, 32)
    float* __restrict__ out)            // (B, 67, M, 32)
{
#pragma clang fp contract(off)
    const int lane  = threadIdx.x & 63;
    const int wv    = threadIdx.x >> 6;
    const int q     = blockIdx.x * WPB + wv;
    const int b     = q >> 11;
    const int m     = q & (Mc - 1);
    const int s     = lane & 31;
    const int chalf = lane >> 5;

    const int myid = idxws[(size_t)q * Sc + s];        // coalesced (both halves)
    const float* nz = new_xyz + (size_t)(b * Mc + m) * 3;
    const float* xb = xyz + (size_t)b * Nc * 3;
    float* ob = out + ((size_t)b * 67 * Mc + m) * Sc;

    // xyz channels 0..2 (centered)
    {
        const float ctr = (chalf == 0) ? nz[0] : nz[1];
        ob[(size_t)chalf * (Mc * Sc) + s] = xb[(size_t)myid * 3 + chalf] - ctr;
    }
    if (chalf == 0)
        ob[(size_t)2 * (Mc * Sc) + s] = xb[(size_t)myid * 3 + 2] - nz[2];

    // feature channels: each sample's 64 channels are one contiguous 256B row
    const float* ftb = featT + ((size_t)b * Nc + myid) * Cc;
    #pragma unroll
    for (int it = 0; it < 8; ++it) {
        const int c4 = it * 2 + chalf;                  // 0..15
        const float4 v = *(const float4*)(ftb + c4 * 4);
        #pragma unroll
        for (int k = 0; k < 4; ++k)
            ob[(size_t)(3 + c4 * 4 + k) * (Mc * Sc) + s] = ((const float*)&v)[k];
    }
}

// Fallback (ws too small): R1's fused kernel with direct (C,N) gather.
__global__ __launch_bounds__(256) void qg_fallback_kernel(
    const float* __restrict__ xyz, const float* __restrict__ new_xyz,
    const float* __restrict__ feat, float* __restrict__ out)
{
#pragma clang fp contract(off)
    const int lane = threadIdx.x & 63;
    const int wv   = threadIdx.x >> 6;
    const int q    = blockIdx.x * WPB + wv;
    const int b    = q >> 11;
    const int m    = q & (Mc - 1);
    __shared__ int sidx[WPB][Sc];
    const float r2 = 0.2f * 0.2f;
    const float* nz = new_xyz + (size_t)(b * Mc + m) * 3;
    const float qx = nz[0], qy = nz[1], qz = nz[2];
    const float* xb = xyz + (size_t)b * Nc * 3;
    int count = 0, firstIdx = 0;
    const unsigned long long lt = (1ull << lane) - 1ull;
    for (int base = 0; base < Nc; base += 64) {
        const int i = base + lane;
        const float px = xb[i * 3], py = xb[i * 3 + 1], pz = xb[i * 3 + 2];
        const float dx = qx - px, dy = qy - py, dz = qz - pz;
        float d2 = dx * dx + dy * dy; d2 = d2 + dz * dz;
        const bool in = d2 < r2;
        const unsigned long long mask = __ballot(in);
        if (in) {
            const int slot = count + __popcll(mask & lt);
            if (slot < Sc) sidx[wv][slot] = i;
        }
        if (count == 0 && mask != 0ull) firstIdx = base + __builtin_ctzll(mask);
        count += __popcll(mask);
        if (count >= Sc) break;
    }
    const int start = count < Sc ? count : Sc;
    if (start + lane < Sc) sidx[wv][start + lane] = firstIdx;
    asm volatile("s_waitcnt lgkmcnt(0)" ::: "memory");
    const int s = lane & 31, chalf = lane >> 5;
    const int myid = sidx[wv][s];
    float* ob = out + ((size_t)b * 67 * Mc + m) * Sc;
    #pragma unroll
    for (int it = 0; it < 2; ++it) {
        const int c = it * 2 + chalf;
        if (c < 3) {
            const float ctr = (c == 0) ? qx : (c == 1) ? qy : qz;
            ob[(size_t)c * (Mc * Sc) + s] = xb[(size_t)myid * 3 + c] - ctr;
        }
    }
    const float* fb = feat + (size_t)b * Cc * Nc;
    #pragma unroll
    for (int it = 0; it < 32; ++it) {
        const int c = it * 2 + chalf;
        ob[(size_t)(3 + c) * (Mc * Sc) + s] = fb[(size_t)c * Nc + myid];
    }
}

extern "C" void kernel_launch(void* const* d_in, const int* in_sizes, int n_in,
                              void* d_out, int out_size, void* d_ws, size_t ws_size,
                              hipStream_t stream) {
    const float* xyz     = (const float*)d_in[0];
    const float* new_xyz = (const float*)d_in[1];
    const float* feat    = (const float*)d_in[2];
    float* out           = (float*)d_out;

    const size_t featT_bytes = (size_t)Bc * Nc * Cc * sizeof(float);   // 16.8 MB
    const size_t idx_bytes   = (size_t)Bc * Mc * Sc * sizeof(int);     //  1.0 MB

    if (ws_size >= featT_bytes + idx_bytes) {
        float* featT = (float*)d_ws;
        int*   idxws = (int*)((char*)d_ws + featT_bytes);
        hipLaunchKernelGGL(prep_kernel, dim3(TBLOCKS + SBLOCKS), dim3(256), 0, stream,
                           xyz, new_xyz, feat, featT, idxws);
        hipLaunchKernelGGL(gather_kernel, dim3(SBLOCKS), dim3(256), 0, stream,
                           xyz, new_xyz, featT, idxws, out);
    } else {
        hipLaunchKernelGGL(qg_fallback_kernel, dim3(SBLOCKS), dim3(256), 0, stream,
                           xyz, new_xyz, feat, out);
    }
}